// Round 1
// 7597.430 us; speedup vs baseline: 1.0605x; 1.0605x over previous
//
#include <hip/hip_runtime.h>

#define BATCH 128
#define SEQ   256
#define IDIM  512
#define HDIM  768
#define G4    3072
#define BK    32

typedef __bf16 bf16;
typedef __bf16 bf16x8 __attribute__((ext_vector_type(8)));
typedef float  f32x4  __attribute__((ext_vector_type(4)));

__device__ __forceinline__ float sigf(float x){ return 1.f/(1.f + __expf(-x)); }
__device__ __forceinline__ float tanhf_(float x){ return 1.f - 2.f/(1.f + __expf(2.f*x)); }

// direct global->LDS, 16B per lane. LDS dest = wave-uniform base + lane*16.
__device__ __forceinline__ void gll16(const bf16* g, bf16* l){
  __builtin_amdgcn_global_load_lds(
      (const __attribute__((address_space(1))) void*)g,
      (__attribute__((address_space(3))) void*)l, 16, 0, 0);
}

// ---- prep kernels -------------------------------------------------------

__global__ void convert_x_k(const float* __restrict__ x, bf16* __restrict__ xb){
  long i = ((long)blockIdx.x*256 + threadIdx.x)*8;
  float4 a = *(const float4*)(x+i);
  float4 b = *(const float4*)(x+i+4);
  bf16x8 o;
  o[0]=(bf16)a.x; o[1]=(bf16)a.y; o[2]=(bf16)a.z; o[3]=(bf16)a.w;
  o[4]=(bf16)b.x; o[5]=(bf16)b.y; o[6]=(bf16)b.z; o[7]=(bf16)b.w;
  *(bf16x8*)(xb+i) = o;
}

// Wt[c][k] (row-major, stride kc) = W[k][g*H+j], c = (j>>4)*64 + g*16 + (j&15)
// rows k<k0 come from Wx, else Wh. bf16.
__global__ void build_wt_k(const float* __restrict__ wx, const float* __restrict__ wh,
                           bf16* __restrict__ wt, int k0, int kc){
  int idx = blockIdx.x*256 + threadIdx.x;
  int c = idx / kc;
  int k = idx - c*kc;
  int g = (c >> 4) & 3;
  int j = ((c >> 6) << 4) | (c & 15);
  int oc = g*HDIM + j;
  float v = (k < k0) ? wx[(long)k*G4 + oc] : wh[(long)(k-k0)*G4 + oc];
  wt[idx] = (bf16)v;
}

__global__ void build_bias_k(const float* __restrict__ bx, const float* __restrict__ bh,
                             float* __restrict__ bc){
  int c = blockIdx.x*256 + threadIdx.x;
  int g = (c >> 4) & 3;
  int j = ((c >> 6) << 4) | (c & 15);
  int oc = g*HDIM + j;
  bc[c] = bx[oc] + bh[oc];
}

// ---- recurrent step -----------------------------------------------------

struct CellP {
  const bf16* seg0;   // input at this timestep, row stride s0stride, k0 cols
  const bf16* seg1;   // h_prev [B,H], row stride HDIM
  const bf16* wt;     // [3072][kc] permuted/transposed weights
  const float* bias;  // [3072] permuted bx+bh
  float* cbuf;        // [B,H] fp32 cell state
  bf16*  hout;        // hseq slice for this t: [B,H]
  float* out;         // layer1: d_out + s*2H (+H for bwd); row stride S*2H. else null
  float* hn;          // final-step h_n slice or null
  float* cn;          // final-step c_n slice or null
  int s0stride, k0, kc, active;
};
struct StepArgs { CellP cell[4]; };

__launch_bounds__(256, 2)
__global__ void lstm_step_k(StepArgs args){
  const CellP p = args.cell[blockIdx.x / 48];
  if (!p.active) return;
  int r = blockIdx.x % 48;
  int mtile = r / 24, ntile = r % 24;        // M: 2x64, N: 24x128
  int tid = threadIdx.x;
  int lane = tid & 63, w = tid >> 6;
  int wm = w >> 1, wn = w & 1;               // waves 2x2, wave tile 32x64
  int l15 = lane & 15, q = lane >> 4;

  // 4-deep LDS ring, linear layout (global_load_lds requires it).
  // Bank-conflict-free via XOR chunk swizzle baked into the per-lane
  // GLOBAL source address (rule #21: swizzle both sides or neither).
  __shared__ __align__(16) bf16 sA[4][64*BK];    // 16 KB
  __shared__ __align__(16) bf16 sB[4][128*BK];   // 32 KB

  f32x4 acc[2][4] = {};

  // staging geometry: each 1024B LDS region = 16 rows x 32 bf16.
  // lane -> (row = l>>2, slot = l&3); logical chunk = slot ^ ((row within region >>1)&3)
  int rl  = lane >> 2;                      // 0..15 row within region
  int lch = (lane & 3) ^ ((lane >> 3) & 3); // logical 8-elem chunk this lane fetches

  int ra = w*16 + rl;                       // A row within 64-row tile (1 region/wave)
  int ga = mtile*64 + ra;
  const bf16* a0 = p.seg0 + (long)ga * p.s0stride + lch*8;
  const bf16* a1 = p.seg1 + (long)ga * HDIM + lch*8 - p.k0;  // valid only when kb*BK >= k0

  long ncol0 = (long)ntile*128;
  const bf16* b0p = p.wt + (ncol0 + w*16     + rl) * (long)p.kc + lch*8;  // B regions w, w+4
  const bf16* b1p = p.wt + (ncol0 + (w+4)*16 + rl) * (long)p.kc + lch*8;

  bf16* sAw  = &sA[0][0] + w*512;           // +buf*2048 elems
  bf16* sBw0 = &sB[0][0] + w*512;           // +buf*4096 elems
  bf16* sBw1 = &sB[0][0] + (w+4)*512;

  int nk = p.kc / BK;                       // 40 or 48
  int k0 = p.k0;

  // prologue: stage batches 0..2 into bufs 0..2 (9 vmem ops/wave in flight)
#pragma unroll
  for (int pb = 0; pb < 3; ++pb){
    const bf16* as = (pb*BK < k0) ? (a0 + pb*BK) : (a1 + pb*BK);
    gll16(as,          sAw  + pb*(64*BK));
    gll16(b0p + pb*BK, sBw0 + pb*(128*BK));
    gll16(b1p + pb*BK, sBw1 + pb*(128*BK));
  }

  int psel = (q ^ ((l15 >> 1) & 3)) * 8;    // physical chunk offset for frag reads

  for (int kb = 0; kb < nk; ++kb){
    // wait own oldest batch (3 loads), counted — never drain in steady state
    int rem = nk - 1 - kb;
    if (rem >= 2)      asm volatile("s_waitcnt vmcnt(6)" ::: "memory");
    else if (rem == 1) asm volatile("s_waitcnt vmcnt(3)" ::: "memory");
    else               asm volatile("s_waitcnt vmcnt(0)" ::: "memory");
    __builtin_amdgcn_s_barrier();           // publish batch kb; also guards the
    __builtin_amdgcn_sched_barrier(0);      // buffer staged below (read at kb-1)

    int nb = kb + 3;
    if (nb < nk){
      int buf = nb & 3;
      const bf16* as = (nb*BK < k0) ? (a0 + nb*BK) : (a1 + nb*BK);
      gll16(as,          sAw  + buf*(64*BK));
      gll16(b0p + nb*BK, sBw0 + buf*(128*BK));
      gll16(b1p + nb*BK, sBw1 + buf*(128*BK));
    }

    const bf16* A  = sA[kb & 3];
    const bf16* Bm = sB[kb & 3];
    bf16x8 af[2], bfr[4];
#pragma unroll
    for (int mi = 0; mi < 2; ++mi)
      af[mi] = *(const bf16x8*)(A + (wm*32 + mi*16 + l15)*BK + psel);
#pragma unroll
    for (int ni = 0; ni < 4; ++ni)
      bfr[ni] = *(const bf16x8*)(Bm + (wn*64 + ni*16 + l15)*BK + psel);
#pragma unroll
    for (int mi = 0; mi < 2; ++mi)
#pragma unroll
      for (int ni = 0; ni < 4; ++ni)
        acc[mi][ni] = __builtin_amdgcn_mfma_f32_16x16x32_bf16(af[mi], bfr[ni], acc[mi][ni], 0, 0, 0);
    __builtin_amdgcn_sched_barrier(0);      // keep reads+MFMA inside this iter
  }

  // epilogue: lane holds 4 gates (ni=0..3 -> f,i,g,o) of hidden unit j, 8 batch rows
  int colb = ntile*128 + wn*64;
  int j = ((colb >> 6) << 4) | l15;
  float bias4[4];
#pragma unroll
  for (int ni=0; ni<4; ++ni) bias4[ni] = p.bias[colb + ni*16 + l15];

#pragma unroll
  for (int mi=0; mi<2; ++mi){
    int b0 = mtile*64 + wm*32 + mi*16 + q*4;
#pragma unroll
    for (int rg=0; rg<4; ++rg){
      int b = b0 + rg;
      float fg = acc[mi][0][rg] + bias4[0];
      float ig = acc[mi][1][rg] + bias4[1];
      float gg = acc[mi][2][rg] + bias4[2];
      float og = acc[mi][3][rg] + bias4[3];
      float co = p.cbuf[b*HDIM + j];
      float cn = sigf(fg)*co + sigf(ig)*tanhf_(gg);
      float h  = sigf(og)*tanhf_(cn);
      p.cbuf[b*HDIM + j] = cn;
      p.hout[b*HDIM + j] = (bf16)h;
      if (p.out) p.out[(long)b*(SEQ*2*HDIM) + j] = h;
      if (p.hn){ p.hn[b*HDIM + j] = h; p.cn[b*HDIM + j] = cn; }
    }
  }
}

// ---- host ---------------------------------------------------------------

extern "C" void kernel_launch(void* const* d_in, const int* in_sizes, int n_in,
                              void* d_out, int out_size, void* d_ws, size_t ws_size,
                              hipStream_t stream){
  (void)in_sizes; (void)n_in; (void)out_size; (void)ws_size;
  const float* x = (const float*)d_in[0];
  const float* Wx[4]; const float* bxp[4]; const float* Whp[4]; const float* bhp[4];
  for (int t=0; t<4; ++t){                   // input tag order: f0, f1, b0, b1
    Wx[t]  = (const float*)d_in[1 + 4*t];
    bxp[t] = (const float*)d_in[2 + 4*t];
    Whp[t] = (const float*)d_in[3 + 4*t];
    bhp[t] = (const float*)d_in[4 + 4*t];
  }
  // cell order: 0=f0, 1=b0, 2=f1, 3=b1
  const int tag[4] = {0, 2, 1, 3};
  const int k0c[4] = {IDIM, IDIM, HDIM, HDIM};
  const int kcc[4] = {IDIM+HDIM, IDIM+HDIM, 2*HDIM, 2*HDIM};

  char* ws = (char*)d_ws;
  size_t off = 0;
  auto take = [&](size_t bytes)->char*{ char* pp = ws + off; off += (bytes + 255) & ~(size_t)255; return pp; };

  bf16* xb = (bf16*)take((size_t)BATCH*SEQ*IDIM*2);
  bf16* wt[4];    for (int c=0;c<4;++c) wt[c]   = (bf16*)take((size_t)G4*kcc[c]*2);
  float* bias[4]; for (int c=0;c<4;++c) bias[c] = (float*)take((size_t)G4*4);
  bf16* hseq[4];  for (int c=0;c<4;++c) hseq[c] = (bf16*)take((size_t)SEQ*BATCH*HDIM*2);
  bf16* zeros = (bf16*)take((size_t)BATCH*HDIM*2);
  float* cbuf[4]; for (int c=0;c<4;++c) cbuf[c] = (float*)take((size_t)BATCH*HDIM*4);

  // zeros + 4 cbufs are contiguous (all sizes multiples of 256) -> one memset
  size_t zlen = (size_t)BATCH*HDIM*2 + 4*(size_t)BATCH*HDIM*4;
  hipMemsetAsync(zeros, 0, zlen, stream);

  convert_x_k<<<dim3((BATCH*SEQ*IDIM)/(8*256)), dim3(256), 0, stream>>>(x, xb);
  for (int c=0;c<4;++c)
    build_wt_k<<<dim3((G4*kcc[c])/256), dim3(256), 0, stream>>>(Wx[tag[c]], Whp[tag[c]], wt[c], k0c[c], kcc[c]);
  for (int c=0;c<4;++c)
    build_bias_k<<<dim3(G4/256), dim3(256), 0, stream>>>(bxp[tag[c]], bhp[tag[c]], bias[c]);

  float* outF = (float*)d_out;
  float* hnF  = outF + (size_t)BATCH*SEQ*2*HDIM;
  float* cnF  = hnF + (size_t)4*BATCH*HDIM;
  const int hnidx[4] = {0, 2, 1, 3};          // f0,f1,b0,b1 stacking order in h_n
  const size_t BH = (size_t)BATCH*HDIM;

  for (int kk=0; kk<=SEQ; ++kk){
    StepArgs A;
    for (int c=0; c<2; ++c){                  // layer 0 at t=kk
      CellP& P = A.cell[c];
      int t = (kk < SEQ) ? kk : 0;
      P.active = (kk < SEQ);
      int ts = (c==0) ? t : (SEQ-1-t);        // bwd cell reads reversed x
      P.seg0 = xb + (size_t)ts*IDIM;
      P.s0stride = SEQ*IDIM;
      P.k0 = k0c[c]; P.kc = kcc[c];
      P.seg1 = (t==0) ? zeros : (hseq[c] + (size_t)(t-1)*BH);
      P.wt = wt[c]; P.bias = bias[c]; P.cbuf = cbuf[c];
      P.hout = hseq[c] + (size_t)t*BH;
      P.out = nullptr;
      if (P.active && t == SEQ-1){ P.hn = hnF + hnidx[c]*BH; P.cn = cnF + hnidx[c]*BH; }
      else { P.hn = nullptr; P.cn = nullptr; }
    }
    for (int c=2; c<4; ++c){                  // layer 1 at t=kk-1
      CellP& P = A.cell[c];
      int t = (kk >= 1) ? (kk-1) : 0;
      P.active = (kk >= 1);
      P.seg0 = hseq[c-2] + (size_t)t*BH;
      P.s0stride = HDIM;
      P.k0 = k0c[c]; P.kc = kcc[c];
      P.seg1 = (t==0) ? zeros : (hseq[c] + (size_t)(t-1)*BH);
      P.wt = wt[c]; P.bias = bias[c]; P.cbuf = cbuf[c];
      P.hout = hseq[c] + (size_t)t*BH;
      P.out = (c==2) ? (outF + (size_t)t*2*HDIM)
                     : (outF + (size_t)(SEQ-1-t)*2*HDIM + HDIM);
      if (P.active && t == SEQ-1){ P.hn = hnF + hnidx[c]*BH; P.cn = cnF + hnidx[c]*BH; }
      else { P.hn = nullptr; P.cn = nullptr; }
    }
    lstm_step_k<<<dim3(192), dim3(256), 0, stream>>>(A);
  }
}